// Round 13
// baseline (2091.019 us; speedup 1.0000x reference)
//
#include <hip/hip_runtime.h>
#include <cmath>

#define B_ 4
#define F_ 8
#define P_ 196
#define D_ 768
#define H_ 12
#define HD_ 64
#define L_ 4
#define MLP_ 3072
#define N_ (1 + F_*P_)     // 1569
#define BN_ (B_*N_)        // 6276
#define SCALE_ 0.125f
#define QKVC_ (3*D_)       // 2304

typedef __bf16 bf16x8 __attribute__((ext_vector_type(8)));
typedef float f32x4 __attribute__((ext_vector_type(4)));
typedef const __attribute__((address_space(1))) void* gas_ptr;
typedef __attribute__((address_space(3))) void* las_ptr;

__device__ __forceinline__ unsigned short f2bf(float f) {
  union { __bf16 b; unsigned short u; } cv;
  cv.b = (__bf16)f;
  return cv.u;
}
__device__ __forceinline__ float bf2f(unsigned short u) {
  union { float f; unsigned int i; } cv; cv.i = ((unsigned int)u) << 16; return cv.f;
}
__device__ __forceinline__ unsigned int pk2(float a, float b) {
  return (unsigned int)f2bf(a) | ((unsigned int)f2bf(b) << 16);
}

__device__ __forceinline__ float gelu_exact(float x) {
  return 0.5f * x * (1.0f + erff(x * 0.70710678118654752f));
}

// ---------------------------------------------------------------- weight convert (per layer)
#define SQKV 1769472
#define SPROJ 589824
#define SFC 2359296

__device__ __forceinline__ void cvt_seg(const float* __restrict__ src,
                                        unsigned short* __restrict__ dst,
                                        int n, int t0, int stride) {
  for (int i = t0; i < (n >> 2); i += stride) {
    float4 v = ((const float4*)src)[i];
    ushort4 o;
    o.x = f2bf(v.x); o.y = f2bf(v.y); o.z = f2bf(v.z); o.w = f2bf(v.w);
    ((ushort4*)dst)[i] = o;
  }
}

__global__ __launch_bounds__(256) void cvt_layer_kernel(const float* qt, const float* pt,
                                                        const float* qs, const float* ps,
                                                        const float* f1, const float* f2,
                                                        unsigned short* wb) {
  int t0 = blockIdx.x * blockDim.x + threadIdx.x;
  int stride = gridDim.x * blockDim.x;
  cvt_seg(qt, wb + 0,       SQKV,  t0, stride);
  cvt_seg(pt, wb + 1769472, SPROJ, t0, stride);
  cvt_seg(qs, wb + 2359296, SQKV,  t0, stride);
  cvt_seg(ps, wb + 4128768, SPROJ, t0, stride);
  cvt_seg(f1, wb + 4718592, SFC,   t0, stride);
  cvt_seg(f2, wb + 7077888, SFC,   t0, stride);
}

// ---------------------------------------------------------------- LayerNorm (fp32 in, bf16 out)
__global__ __launch_bounds__(256) void ln_kernel(const float* __restrict__ x,
                                                 const float* __restrict__ g,
                                                 const float* __restrict__ b,
                                                 unsigned short* __restrict__ out) {
  int row = blockIdx.x;
  const float* xr = x + (size_t)row * D_;
  unsigned short* orow = out + (size_t)row * D_;
  int tid = threadIdx.x;
  float v0 = xr[tid], v1 = xr[tid + 256], v2 = xr[tid + 512];
  float s  = v0 + v1 + v2;
  float ss = v0*v0 + v1*v1 + v2*v2;
  #pragma unroll
  for (int o = 32; o > 0; o >>= 1) { s += __shfl_xor(s, o); ss += __shfl_xor(ss, o); }
  __shared__ float sm[8];
  int w = tid >> 6;
  if ((tid & 63) == 0) { sm[w*2] = s; sm[w*2+1] = ss; }
  __syncthreads();
  float tot  = sm[0] + sm[2] + sm[4] + sm[6];
  float tot2 = sm[1] + sm[3] + sm[5] + sm[7];
  float mean = tot * (1.0f/D_);
  float var  = tot2 * (1.0f/D_) - mean*mean;
  float rs   = rsqrtf(var + 1e-5f);
  orow[tid]       = f2bf((v0 - mean)*rs*g[tid]       + b[tid]);
  orow[tid + 256] = f2bf((v1 - mean)*rs*g[tid + 256] + b[tid + 256]);
  orow[tid + 512] = f2bf((v2 - mean)*rs*g[tid + 512] + b[tid + 512]);
}

// ---------------------------------------------------------------- 128x128 4-wave GEMM, 2-buffer 32KB
// Counted vmcnt (stage t+1 stays in flight), two raw barriers per K-step.
// 32 KB LDS -> 5 blocks/CU = 20 waves/CU (was 12 at 48 KB).
// GROUP-M L2 super-tiling (8 M-tiles) after XCD-bijective chunking. Coalesced epilogue.
// C[M,NN] = A[M,K](bf16) @ W[NN,K](bf16)^T, fp32 accumulate.
// EPI 0: fp32 out. EPI 1: +bias+Res fp32 out. EPI 2: gelu(+bias) bf16 out. EPI 3: bf16 out.
template<int EPI>
__global__ __launch_bounds__(256, 5) void mfma_gemmP(const unsigned short* __restrict__ A,
                                                     const unsigned short* __restrict__ W,
                                                     const float* __restrict__ bias,
                                                     const float* __restrict__ Res,
                                                     void* __restrict__ Cout,
                                                     int M, int NN, int K) {
  __shared__ __align__(16) unsigned short LdsRaw[2*2*128*32];   // 32 KB
  unsigned short* LdsA = LdsRaw;                 // 2 bufs x 4096 elems
  unsigned short* LdsB = LdsRaw + 2*128*32;      // 2 bufs x 4096 elems
  int tid = threadIdx.x;
  int w = tid >> 6, l = tid & 63;
  int fr = l & 15, fq = l >> 4;
  int wr = w >> 1, wc = w & 1;
  int gx = (M + 127) >> 7;
  int gy = (NN + 127) >> 7;

  // XCD-bijective chunking (m204), then GROUP-M L2 tiling
  int nwg = gridDim.x;
  int orig = blockIdx.x;
  int q8 = nwg >> 3, r8 = nwg & 7;
  int xcd = orig & 7, idx = orig >> 3;
  int wg = (xcd < r8 ? xcd*(q8+1) : r8*(q8+1) + (xcd-r8)*q8) + idx;
  const int GROUPM = 8;
  int npg = GROUPM * gy;
  int gid = wg / npg;
  int first_m = gid * GROUPM;
  int gsz = gx - first_m; if (gsz > GROUPM) gsz = GROUPM;
  int rem = wg - gid * npg;
  int pid_m = first_m + rem % gsz;
  int pid_n = rem / gsz;
  int m0 = pid_m * 128, n0 = pid_n * 128;

  // staging: chunk c (0..511) -> LDS byte c*16 = row*64 + slot*16 (row=c>>2, slot=c&3)
  // global source column pre-swizzled: cb = (slot<<4) ^ (((row>>1)&3)<<4)
  const char* aSrc[2]; const char* bSrc[2];
  #pragma unroll
  for (int q = 0; q < 2; ++q) {
    int c = q*256 + tid;
    int row = c >> 2;
    int cb = ((c & 3) << 4) ^ (((row >> 1) & 3) << 4);
    int ra = m0 + row; if (ra >= M) ra = M - 1;
    aSrc[q] = (const char*)A + ((size_t)ra * K) * 2 + cb;
    bSrc[q] = (const char*)W + ((size_t)(n0 + row) * K) * 2 + cb;
  }

  f32x4 acc[4][4] = {};
  int nt = K >> 5;
  int lswz = ((fr >> 1) & 3) << 4;

#define STAGEP(buf, kt) do { int kb_ = (kt) * 64;                                                                      \
    __builtin_amdgcn_global_load_lds((gas_ptr)(aSrc[0]+kb_), (las_ptr)(&LdsA[(buf)*4096 + (0*256 + w*64)*8]), 16, 0, 0); \
    __builtin_amdgcn_global_load_lds((gas_ptr)(aSrc[1]+kb_), (las_ptr)(&LdsA[(buf)*4096 + (1*256 + w*64)*8]), 16, 0, 0); \
    __builtin_amdgcn_global_load_lds((gas_ptr)(bSrc[0]+kb_), (las_ptr)(&LdsB[(buf)*4096 + (0*256 + w*64)*8]), 16, 0, 0); \
    __builtin_amdgcn_global_load_lds((gas_ptr)(bSrc[1]+kb_), (las_ptr)(&LdsB[(buf)*4096 + (1*256 + w*64)*8]), 16, 0, 0); \
  } while (0)

  STAGEP(0, 0);
  STAGEP(1, 1);
  int cur = 0;
  for (int t = 0; t < nt; ++t) {
    // stage t complete; stage t+1 (if any) stays in flight (counted wait, never a full drain mid-loop)
    if (t + 1 < nt) {
      asm volatile("s_waitcnt vmcnt(4)" ::: "memory");
    } else {
      asm volatile("s_waitcnt vmcnt(0)" ::: "memory");
    }
    __builtin_amdgcn_s_barrier();
    const char* bufA = (const char*)(LdsA + cur*4096);
    const char* bufB = (const char*)(LdsB + cur*4096);
    bf16x8 afrag[4], bfrag[4];
    #pragma unroll
    for (int n = 0; n < 4; ++n)
      bfrag[n] = *(const bf16x8*)(bufB + (wc*64 + n*16 + fr)*64 + ((fq*16) ^ lswz));
    #pragma unroll
    for (int m = 0; m < 4; ++m)
      afrag[m] = *(const bf16x8*)(bufA + (wr*64 + m*16 + fr)*64 + ((fq*16) ^ lswz));
    #pragma unroll
    for (int m = 0; m < 4; ++m)
      #pragma unroll
      for (int n = 0; n < 4; ++n)
        acc[m][n] = __builtin_amdgcn_mfma_f32_16x16x32_bf16(afrag[m], bfrag[n], acc[m][n], 0, 0, 0);
    // all waves' reads of buf[cur] are lgkm-consumed by the MFMAs above; after this barrier
    // it is safe to overwrite buf[cur] with tile t+2
    __builtin_amdgcn_s_barrier();
    if (t + 2 < nt) {
      STAGEP(cur, t + 2);
    }
    cur ^= 1;
  }
#undef STAGEP

  // ---- coalesced epilogue: two 64-row halves staged through LDS (32 KB, exact fit) ----
  float* eps = (float*)LdsRaw;
  #pragma unroll
  for (int h = 0; h < 2; ++h) {
    __syncthreads();
    if (wr == h) {
      #pragma unroll
      for (int n = 0; n < 4; ++n)
        #pragma unroll
        for (int i = 0; i < 4; ++i)
          #pragma unroll
          for (int r = 0; r < 4; ++r) {
            int lrow = i*16 + fq*4 + r;
            int col  = wc*64 + n*16 + fr;
            eps[lrow*128 + (col ^ (((lrow >> 2) & 7) << 2))] = acc[i][n][r];
          }
    }
    __syncthreads();
    #pragma unroll
    for (int p = 0; p < 8; ++p) {
      int idx = p*256 + tid;
      int lrow = idx >> 5, cg = idx & 31;
      int col0 = cg * 4;
      int grow = m0 + h*64 + lrow;
      if (grow < M) {
        f32x4 v = *(const f32x4*)&eps[lrow*128 + (col0 ^ (((lrow >> 2) & 7) << 2))];
        int gcol = n0 + col0;
        if (EPI == 1 || EPI == 2) {
          float4 bv = *(const float4*)&bias[gcol];
          v[0] += bv.x; v[1] += bv.y; v[2] += bv.z; v[3] += bv.w;
        }
        if (EPI == 1) {
          float4 rv = *(const float4*)&Res[(size_t)grow * NN + gcol];
          v[0] += rv.x; v[1] += rv.y; v[2] += rv.z; v[3] += rv.w;
          *(float4*)&((float*)Cout)[(size_t)grow * NN + gcol] = make_float4(v[0], v[1], v[2], v[3]);
        } else if (EPI == 0) {
          *(float4*)&((float*)Cout)[(size_t)grow * NN + gcol] = make_float4(v[0], v[1], v[2], v[3]);
        } else {
          if (EPI == 2) {
            v[0] = gelu_exact(v[0]); v[1] = gelu_exact(v[1]);
            v[2] = gelu_exact(v[2]); v[3] = gelu_exact(v[3]);
          }
          unsigned long long ov = (unsigned long long)pk2(v[0], v[1])
                                | ((unsigned long long)pk2(v[2], v[3]) << 32);
          *(unsigned long long*)&((unsigned short*)Cout)[(size_t)grow * NN + gcol] = ov;
        }
      }
    }
  }
}

// ---------------------------------------------------------------- cls attention (split-K)
#define CLS_CH 7
#define CLS_CHSZ 256
__global__ __launch_bounds__(256) void cls_attn_part(const unsigned short* __restrict__ qkv,
                                                     float* __restrict__ part) {
  int blk = blockIdx.x;
  int c = blk % CLS_CH, bh = blk / CLS_CH;
  int b = bh / H_, h = bh % H_;
  const unsigned short* base = qkv + (size_t)b * N_ * QKVC_ + h * HD_;
  __shared__ float q[HD_];
  __shared__ float s[CLS_CHSZ];
  __shared__ float redm[4], redd[4];
  __shared__ float pvs[4][HD_];
  int tid = threadIdx.x;
  if (tid < HD_) q[tid] = bf2f(base[tid]) * SCALE_;
  __syncthreads();
  int j = c * CLS_CHSZ + tid;
  float sc = -1e30f;
  if (j < N_) {
    const unsigned short* kp = base + (size_t)j * QKVC_ + D_;
    float acc = 0.f;
    #pragma unroll
    for (int cc = 0; cc < 8; ++cc) {
      uint4 kv = *(const uint4*)(kp + cc*8);
      const unsigned short* e = (const unsigned short*)&kv;
      #pragma unroll
      for (int t = 0; t < 8; ++t) acc = fmaf(q[cc*8+t], bf2f(e[t]), acc);
    }
    sc = acc;
  }
  float m = sc;
  #pragma unroll
  for (int o = 32; o > 0; o >>= 1) m = fmaxf(m, __shfl_xor(m, o));
  if ((tid & 63) == 0) redm[tid >> 6] = m;
  __syncthreads();
  m = fmaxf(fmaxf(redm[0], redm[1]), fmaxf(redm[2], redm[3]));
  float p = (j < N_) ? __expf(sc - m) : 0.f;
  s[tid] = p;
  float den = p;
  #pragma unroll
  for (int o = 32; o > 0; o >>= 1) den += __shfl_xor(den, o);
  if ((tid & 63) == 0) redd[tid >> 6] = den;
  __syncthreads();
  float dtot = redd[0] + redd[1] + redd[2] + redd[3];
  int lane = tid & 63, g = tid >> 6;
  float acc = 0.f;
  #pragma unroll 8
  for (int i = 0; i < CLS_CHSZ/4; ++i) {
    int jl = g + 4*i;
    int jj = c * CLS_CHSZ + jl;
    if (jj < N_) acc = fmaf(s[jl], bf2f(base[(size_t)jj * QKVC_ + 2*D_ + lane]), acc);
  }
  pvs[g][lane] = acc;
  __syncthreads();
  if (g == 0) {
    float pv = pvs[0][lane] + pvs[1][lane] + pvs[2][lane] + pvs[3][lane];
    float* pp = part + ((size_t)bh * CLS_CH + c) * 66;
    if (lane == 0) { pp[0] = m; pp[1] = dtot; }
    pp[2 + lane] = pv;
  }
}

__global__ __launch_bounds__(64) void cls_attn_reduce(const float* __restrict__ part,
                                                      unsigned short* __restrict__ att) {
  int bh = blockIdx.x;
  int b = bh / H_, h = bh % H_;
  int lane = threadIdx.x;
  const float* pp = part + (size_t)bh * CLS_CH * 66;
  float m = -1e30f;
  #pragma unroll
  for (int c = 0; c < CLS_CH; ++c) m = fmaxf(m, pp[c*66]);
  float den = 0.f, acc = 0.f;
  #pragma unroll
  for (int c = 0; c < CLS_CH; ++c) {
    float wfac = __expf(pp[c*66] - m);
    den += pp[c*66 + 1] * wfac;
    acc += pp[c*66 + 2 + lane] * wfac;
  }
  att[(size_t)(b * N_) * D_ + h * HD_ + lane] = f2bf(acc / den);
}

// ---------------------------------------------------------------- space attention (MFMA)
__global__ __launch_bounds__(256) void space_attn_mfma(const unsigned short* __restrict__ qkv,
                                                       unsigned short* __restrict__ att) {
  int blk = blockIdx.x;
  int f = blk % F_; int bh = blk / F_;
  int b = bh / H_, h = bh % H_;
  const unsigned short* qbase = qkv + (size_t)b * N_ * QKVC_ + h * HD_;
  __shared__ __align__(16) unsigned short Ksm[208*64];
  __shared__ __align__(16) unsigned short Vtm[64*256];
  __shared__ __align__(16) unsigned short Pm[4*16*256];
  int tid = threadIdx.x;

  for (int c = tid; c < 208*8; c += 256) {
    int j = c >> 3, cb = (c & 7) * 16;
    uint4 val = make_uint4(0,0,0,0);
    if (j < 197) {
      int n = (j == 0) ? 0 : (1 + f*P_ + j - 1);
      val = *(const uint4*)(qbase + (size_t)n*QKVC_ + D_ + cb/2);
    }
    *(uint4*)((char*)Ksm + j*128 + (cb ^ ((j&7)<<4))) = val;
  }
  for (int c = tid; c < 112*8; c += 256) {
    int jj = c % 112, dc = c / 112;
    int j0 = jj * 2;
    uint4 r0 = make_uint4(0,0,0,0), r1 = make_uint4(0,0,0,0);
    if (j0 < 197) {
      int n = (j0 == 0) ? 0 : (1 + f*P_ + j0 - 1);
      r0 = *(const uint4*)(qbase + (size_t)n*QKVC_ + 2*D_ + dc*8);
    }
    if (j0 + 1 < 197) {
      int n = 1 + f*P_ + j0;
      r1 = *(const uint4*)(qbase + (size_t)n*QKVC_ + 2*D_ + dc*8);
    }
    const unsigned short* e0 = (const unsigned short*)&r0;
    const unsigned short* e1 = (const unsigned short*)&r1;
    #pragma unroll
    for (int e = 0; e < 8; ++e) {
      int d = dc*8 + e;
      unsigned int pk = (unsigned int)e0[e] | ((unsigned int)e1[e] << 16);
      *(unsigned int*)((char*)Vtm + d*512 + ((2*j0) ^ ((d&7)<<4))) = pk;
    }
  }
  int w = tid >> 6, l = tid & 63;
  int fr = l & 15, fq = l >> 4;
  char* Pw = (char*)Pm + w * 8192;
  {
    int q = l >> 2, cb = 416 + (l & 3) * 8;
    *(unsigned long long*)(Pw + q*512 + (cb ^ ((q&7)<<4))) = 0ull;
  }
  __syncthreads();

  int swz = (fr & 7) << 4;
  for (int qt = w; qt <= 12; qt += 4) {
    int qrow = qt*16 + fr; if (qrow > 195) qrow = 195;
    int n_q = 1 + f*P_ + qrow;
    bf16x8 qf0 = *(const bf16x8*)(qbase + (size_t)n_q*QKVC_ + fq*8);
    bf16x8 qf1 = *(const bf16x8*)(qbase + (size_t)n_q*QKVC_ + 32 + fq*8);
    f32x4 s[13];
    #pragma unroll
    for (int jt = 0; jt < 13; ++jt) s[jt] = (f32x4){0.f,0.f,0.f,0.f};
    #pragma unroll
    for (int jt = 0; jt < 13; ++jt) {
      bf16x8 a0 = *(const bf16x8*)((char*)Ksm + (jt*16+fr)*128 + ((fq*16) ^ swz));
      s[jt] = __builtin_amdgcn_mfma_f32_16x16x32_bf16(a0, qf0, s[jt], 0, 0, 0);
      bf16x8 a1 = *(const bf16x8*)((char*)Ksm + (jt*16+fr)*128 + ((64 + fq*16) ^ swz));
      s[jt] = __builtin_amdgcn_mfma_f32_16x16x32_bf16(a1, qf1, s[jt], 0, 0, 0);
    }
    float m = -1e30f;
    #pragma unroll
    for (int jt = 0; jt < 13; ++jt) {
      #pragma unroll
      for (int r = 0; r < 4; ++r) {
        if (jt*16 + fq*4 + r < 197) m = fmaxf(m, s[jt][r]);
      }
    }
    m = fmaxf(m, __shfl_xor(m, 16));
    m = fmaxf(m, __shfl_xor(m, 32));
    float den = 0.f;
    #pragma unroll
    for (int jt = 0; jt < 13; ++jt) {
      #pragma unroll
      for (int r = 0; r < 4; ++r) {
        float p = (jt*16 + fq*4 + r < 197) ? __expf((s[jt][r] - m) * SCALE_) : 0.f;
        s[jt][r] = p;
        den += p;
      }
    }
    den += __shfl_xor(den, 16);
    den += __shfl_xor(den, 32);
    #pragma unroll
    for (int jt = 0; jt < 13; ++jt) {
      unsigned long long pv = (unsigned long long)pk2(s[jt][0], s[jt][1])
                            | ((unsigned long long)pk2(s[jt][2], s[jt][3]) << 32);
      *(unsigned long long*)(Pw + fr*512 + ((jt*32 + fq*8) ^ swz)) = pv;
    }
    float rden = 1.0f / den;
    bool wr_ok = (qt*16 + fr) < 196;
    int n_out = 1 + f*P_ + qt*16 + fr;
    #pragma unroll
    for (int dt = 0; dt < 4; ++dt) {
      f32x4 o = (f32x4){0.f,0.f,0.f,0.f};
      #pragma unroll
      for (int ks = 0; ks < 7; ++ks) {
        bf16x8 av = *(const bf16x8*)((char*)Vtm + (dt*16+fr)*512 + ((ks*64 + fq*16) ^ swz));
        bf16x8 bp = *(const bf16x8*)(Pw + fr*512 + ((ks*64 + fq*16) ^ swz));
        o = __builtin_amdgcn_mfma_f32_16x16x32_bf16(av, bp, o, 0, 0, 0);
      }
      if (wr_ok) {
        unsigned long long ov = (unsigned long long)pk2(o[0]*rden, o[1]*rden)
                              | ((unsigned long long)pk2(o[2]*rden, o[3]*rden) << 32);
        *(unsigned long long*)(att + (size_t)(b*N_ + n_out)*D_ + h*HD_ + dt*16 + fq*4) = ov;
      }
    }
  }
}

// ---------------------------------------------------------------- time attention (bf16 qkv)
__global__ __launch_bounds__(256) void time_attn_kernel(const unsigned short* __restrict__ qkv,
                                                        unsigned short* __restrict__ att) {
  int idx = blockIdx.x * 4 + (threadIdx.x >> 6);
  int bh = idx / P_, p = idx % P_;
  int b = bh / H_, h = bh % H_;
  int lane = threadIdx.x & 63;
  const unsigned short* base = qkv + (size_t)b * N_ * QKVC_ + h * HD_ + lane;
  float k[9], v[9];
  k[0] = bf2f(base[D_]);
  v[0] = bf2f(base[2*D_]);
  #pragma unroll
  for (int j = 0; j < 8; ++j) {
    size_t r = (size_t)(1 + j * P_ + p) * QKVC_;
    k[j+1] = bf2f(base[r + D_]);
    v[j+1] = bf2f(base[r + 2*D_]);
  }
  #pragma unroll 1
  for (int f = 0; f < F_; ++f) {
    size_t qr = (size_t)(1 + f * P_ + p) * QKVC_;
    float qd = bf2f(base[qr]) * SCALE_;
    float s[9];
    #pragma unroll
    for (int j = 0; j < 9; ++j) {
      float prod = qd * k[j];
      #pragma unroll
      for (int o = 32; o > 0; o >>= 1) prod += __shfl_xor(prod, o);
      s[j] = prod;
    }
    float m = s[0];
    #pragma unroll
    for (int j = 1; j < 9; ++j) m = fmaxf(m, s[j]);
    float den = 0.f, o_ = 0.f;
    #pragma unroll
    for (int j = 0; j < 9; ++j) {
      float pj = __expf(s[j] - m);
      den += pj;
      o_ = fmaf(pj, v[j], o_);
    }
    att[(size_t)(b * N_ + 1 + f * P_ + p) * D_ + h * HD_ + lane] = f2bf(o_ / den);
  }
}

// ---------------------------------------------------------------- launcher
extern "C" void kernel_launch(void* const* d_in, const int* in_sizes, int n_in,
                              void* d_out, int out_size, void* d_ws, size_t ws_size,
                              hipStream_t stream) {
  const float* x_in     = (const float*)d_in[0];
  const float* qkv_w_t  = (const float*)d_in[1];
  const float* proj_w_t = (const float*)d_in[2];
  const float* proj_b_t = (const float*)d_in[3];
  const float* qkv_w_s  = (const float*)d_in[4];
  const float* proj_w_s = (const float*)d_in[5];
  const float* proj_b_s = (const float*)d_in[6];
  const float* fc1_w    = (const float*)d_in[7];
  const float* fc1_b    = (const float*)d_in[8];
  const float* fc2_w    = (const float*)d_in[9];
  const float* fc2_b    = (const float*)d_in[10];
  const float* ln1_g    = (const float*)d_in[11];
  const float* ln1_b    = (const float*)d_in[12];
  const float* ln2_g    = (const float*)d_in[13];
  const float* ln2_b    = (const float*)d_in[14];
  const float* ln3_g    = (const float*)d_in[15];
  const float* ln3_b    = (const float*)d_in[16];

  float* X_out = (float*)d_out;
  char* ws = (char*)d_ws;
  unsigned short* Wbf = (unsigned short*)ws;
  const size_t WOFF = 18874368;
  unsigned short* QKVbf = (unsigned short*)(ws + WOFF);
  unsigned short* Hbf   = (unsigned short*)(ws + WOFF);
  float*          TR    = (float*)(ws + WOFF + 57839616);
  unsigned short* Abf   = (unsigned short*)(ws + WOFF + 57839616 + 19279872);
  float*          CLSP  = (float*)(ws + WOFF + 57839616 + 19279872 + 9639936);

  unsigned short* wqkv_t = Wbf + 0;
  unsigned short* wproj_t= Wbf + 1769472;
  unsigned short* wqkv_s = Wbf + 2359296;
  unsigned short* wproj_s= Wbf + 4128768;
  unsigned short* wfc1   = Wbf + 4718592;
  unsigned short* wfc2   = Wbf + 7077888;

  dim3 blk(256);
  // 128x128 tile grids (flattened 1-D): gx = ceil(6276/128) = 50
  dim3 g_qkv(50 * 18), g_proj(50 * 6), g_fc1(50 * 24), g_fc2(50 * 6);

  for (int l = 0; l < L_; ++l) {
    const float* X = (l == 0) ? x_in : (const float*)X_out;
    cvt_layer_kernel<<<2048, blk, 0, stream>>>(
        qkv_w_t + (size_t)l*SQKV, proj_w_t + (size_t)l*SPROJ,
        qkv_w_s + (size_t)l*SQKV, proj_w_s + (size_t)l*SPROJ,
        fc1_w + (size_t)l*SFC, fc2_w + (size_t)l*SFC, Wbf);
    // 1. a = LN3(x)
    ln_kernel<<<BN_, blk, 0, stream>>>(X, ln3_g + l*D_, ln3_b + l*D_, Abf);
    // 2. qkv_t (bf16 out)
    mfma_gemmP<3><<<g_qkv, blk, 0, stream>>>(Abf, wqkv_t, nullptr, nullptr, QKVbf, BN_, QKVC_, D_);
    // 3/4. time attention (+ cls)
    cls_attn_part<<<B_*H_*CLS_CH, blk, 0, stream>>>(QKVbf, CLSP);
    cls_attn_reduce<<<B_*H_, dim3(64), 0, stream>>>(CLSP, Abf);
    time_attn_kernel<<<(B_*H_*P_)/4, blk, 0, stream>>>(QKVbf, Abf);
    // 5. time_residual = x + att @ proj_w_t^T + b
    mfma_gemmP<1><<<g_proj, blk, 0, stream>>>(Abf, wproj_t, proj_b_t + l*D_, X, TR, BN_, D_, D_);
    // 6. a = LN1(time_residual)
    ln_kernel<<<BN_, blk, 0, stream>>>(TR, ln1_g + l*D_, ln1_b + l*D_, Abf);
    // 7. qkv_s (bf16 out)
    mfma_gemmP<3><<<g_qkv, blk, 0, stream>>>(Abf, wqkv_s, nullptr, nullptr, QKVbf, BN_, QKVC_, D_);
    // 8/9. space attention (+ cls)
    cls_attn_part<<<B_*H_*CLS_CH, blk, 0, stream>>>(QKVbf, CLSP);
    cls_attn_reduce<<<B_*H_, dim3(64), 0, stream>>>(CLSP, Abf);
    space_attn_mfma<<<B_*H_*F_, blk, 0, stream>>>(QKVbf, Abf);
    // 10. space_residual = x + att @ proj_w_s^T + b
    mfma_gemmP<1><<<g_proj, blk, 0, stream>>>(Abf, wproj_s, proj_b_s + l*D_, X, TR, BN_, D_, D_);
    // 11. a = LN2(space_residual)
    ln_kernel<<<BN_, blk, 0, stream>>>(TR, ln2_g + l*D_, ln2_b + l*D_, Abf);
    // 12. h = gelu(a @ fc1^T + b)  (bf16 out)
    mfma_gemmP<2><<<g_fc1, blk, 0, stream>>>(Abf, wfc1, fc1_b + l*MLP_, nullptr, Hbf, BN_, MLP_, D_);
    // 13. out = space_residual + h @ fc2^T + b
    mfma_gemmP<1><<<g_fc2, blk, 0, stream>>>(Hbf, wfc2, fc2_b + l*D_, TR, X_out, BN_, D_, MLP_);
  }
}

// Round 14
// 1543.512 us; speedup vs baseline: 1.3547x; 1.3547x over previous
//
#include <hip/hip_runtime.h>
#include <cmath>

#define B_ 4
#define F_ 8
#define P_ 196
#define D_ 768
#define H_ 12
#define HD_ 64
#define L_ 4
#define MLP_ 3072
#define N_ (1 + F_*P_)     // 1569
#define BN_ (B_*N_)        // 6276
#define SCALE_ 0.125f
#define QKVC_ (3*D_)       // 2304

typedef __bf16 bf16x8 __attribute__((ext_vector_type(8)));
typedef float f32x4 __attribute__((ext_vector_type(4)));
typedef const __attribute__((address_space(1))) void* gas_ptr;
typedef __attribute__((address_space(3))) void* las_ptr;

__device__ __forceinline__ unsigned short f2bf(float f) {
  union { __bf16 b; unsigned short u; } cv;
  cv.b = (__bf16)f;
  return cv.u;
}
__device__ __forceinline__ float bf2f(unsigned short u) {
  union { float f; unsigned int i; } cv; cv.i = ((unsigned int)u) << 16; return cv.f;
}
__device__ __forceinline__ unsigned int pk2(float a, float b) {
  return (unsigned int)f2bf(a) | ((unsigned int)f2bf(b) << 16);
}

__device__ __forceinline__ float gelu_exact(float x) {
  return 0.5f * x * (1.0f + erff(x * 0.70710678118654752f));
}

// ---------------------------------------------------------------- weight convert (per layer)
#define SQKV 1769472
#define SPROJ 589824
#define SFC 2359296

__device__ __forceinline__ void cvt_seg(const float* __restrict__ src,
                                        unsigned short* __restrict__ dst,
                                        int n, int t0, int stride) {
  for (int i = t0; i < (n >> 2); i += stride) {
    float4 v = ((const float4*)src)[i];
    ushort4 o;
    o.x = f2bf(v.x); o.y = f2bf(v.y); o.z = f2bf(v.z); o.w = f2bf(v.w);
    ((ushort4*)dst)[i] = o;
  }
}

__global__ __launch_bounds__(256) void cvt_layer_kernel(const float* qt, const float* pt,
                                                        const float* qs, const float* ps,
                                                        const float* f1, const float* f2,
                                                        unsigned short* wb) {
  int t0 = blockIdx.x * blockDim.x + threadIdx.x;
  int stride = gridDim.x * blockDim.x;
  cvt_seg(qt, wb + 0,       SQKV,  t0, stride);
  cvt_seg(pt, wb + 1769472, SPROJ, t0, stride);
  cvt_seg(qs, wb + 2359296, SQKV,  t0, stride);
  cvt_seg(ps, wb + 4128768, SPROJ, t0, stride);
  cvt_seg(f1, wb + 4718592, SFC,   t0, stride);
  cvt_seg(f2, wb + 7077888, SFC,   t0, stride);
}

// ---------------------------------------------------------------- LayerNorm (fp32 in, bf16 out)
__global__ __launch_bounds__(256) void ln_kernel(const float* __restrict__ x,
                                                 const float* __restrict__ g,
                                                 const float* __restrict__ b,
                                                 unsigned short* __restrict__ out) {
  int row = blockIdx.x;
  const float* xr = x + (size_t)row * D_;
  unsigned short* orow = out + (size_t)row * D_;
  int tid = threadIdx.x;
  float v0 = xr[tid], v1 = xr[tid + 256], v2 = xr[tid + 512];
  float s  = v0 + v1 + v2;
  float ss = v0*v0 + v1*v1 + v2*v2;
  #pragma unroll
  for (int o = 32; o > 0; o >>= 1) { s += __shfl_xor(s, o); ss += __shfl_xor(ss, o); }
  __shared__ float sm[8];
  int w = tid >> 6;
  if ((tid & 63) == 0) { sm[w*2] = s; sm[w*2+1] = ss; }
  __syncthreads();
  float tot  = sm[0] + sm[2] + sm[4] + sm[6];
  float tot2 = sm[1] + sm[3] + sm[5] + sm[7];
  float mean = tot * (1.0f/D_);
  float var  = tot2 * (1.0f/D_) - mean*mean;
  float rs   = rsqrtf(var + 1e-5f);
  orow[tid]       = f2bf((v0 - mean)*rs*g[tid]       + b[tid]);
  orow[tid + 256] = f2bf((v1 - mean)*rs*g[tid + 256] + b[tid + 256]);
  orow[tid + 512] = f2bf((v2 - mean)*rs*g[tid + 512] + b[tid + 512]);
}

// ---------------------------------------------------------------- 128x128 4-wave GEMM, 2-buffer 32KB
// Counted vmcnt (stage t+1 stays in flight), two raw barriers per K-step.
// 32 KB LDS, __launch_bounds__(256,4): 4 blocks/CU = 16 waves/CU, VGPR cap 128 (no spill).
// GROUP-M L2 super-tiling (8 M-tiles) after XCD-bijective chunking. Coalesced epilogue.
// C[M,NN] = A[M,K](bf16) @ W[NN,K](bf16)^T, fp32 accumulate.
// EPI 0: fp32 out. EPI 1: +bias+Res fp32 out. EPI 2: gelu(+bias) bf16 out. EPI 3: bf16 out.
template<int EPI>
__global__ __launch_bounds__(256, 4) void mfma_gemmP(const unsigned short* __restrict__ A,
                                                     const unsigned short* __restrict__ W,
                                                     const float* __restrict__ bias,
                                                     const float* __restrict__ Res,
                                                     void* __restrict__ Cout,
                                                     int M, int NN, int K) {
  __shared__ __align__(16) unsigned short LdsRaw[2*2*128*32];   // 32 KB
  unsigned short* LdsA = LdsRaw;                 // 2 bufs x 4096 elems
  unsigned short* LdsB = LdsRaw + 2*128*32;      // 2 bufs x 4096 elems
  int tid = threadIdx.x;
  int w = tid >> 6, l = tid & 63;
  int fr = l & 15, fq = l >> 4;
  int wr = w >> 1, wc = w & 1;
  int gx = (M + 127) >> 7;
  int gy = (NN + 127) >> 7;

  // XCD-bijective chunking (m204), then GROUP-M L2 tiling
  int nwg = gridDim.x;
  int orig = blockIdx.x;
  int q8 = nwg >> 3, r8 = nwg & 7;
  int xcd = orig & 7, idx = orig >> 3;
  int wg = (xcd < r8 ? xcd*(q8+1) : r8*(q8+1) + (xcd-r8)*q8) + idx;
  const int GROUPM = 8;
  int npg = GROUPM * gy;
  int gid = wg / npg;
  int first_m = gid * GROUPM;
  int gsz = gx - first_m; if (gsz > GROUPM) gsz = GROUPM;
  int rem = wg - gid * npg;
  int pid_m = first_m + rem % gsz;
  int pid_n = rem / gsz;
  int m0 = pid_m * 128, n0 = pid_n * 128;

  // staging: chunk c (0..511) -> LDS byte c*16 = row*64 + slot*16 (row=c>>2, slot=c&3)
  // global source column pre-swizzled: cb = (slot<<4) ^ (((row>>1)&3)<<4)
  const char* aSrc[2]; const char* bSrc[2];
  #pragma unroll
  for (int q = 0; q < 2; ++q) {
    int c = q*256 + tid;
    int row = c >> 2;
    int cb = ((c & 3) << 4) ^ (((row >> 1) & 3) << 4);
    int ra = m0 + row; if (ra >= M) ra = M - 1;
    aSrc[q] = (const char*)A + ((size_t)ra * K) * 2 + cb;
    bSrc[q] = (const char*)W + ((size_t)(n0 + row) * K) * 2 + cb;
  }

  f32x4 acc[4][4] = {};
  int nt = K >> 5;
  int lswz = ((fr >> 1) & 3) << 4;

#define STAGEP(buf, kt) do { int kb_ = (kt) * 64;                                                                      \
    __builtin_amdgcn_global_load_lds((gas_ptr)(aSrc[0]+kb_), (las_ptr)(&LdsA[(buf)*4096 + (0*256 + w*64)*8]), 16, 0, 0); \
    __builtin_amdgcn_global_load_lds((gas_ptr)(aSrc[1]+kb_), (las_ptr)(&LdsA[(buf)*4096 + (1*256 + w*64)*8]), 16, 0, 0); \
    __builtin_amdgcn_global_load_lds((gas_ptr)(bSrc[0]+kb_), (las_ptr)(&LdsB[(buf)*4096 + (0*256 + w*64)*8]), 16, 0, 0); \
    __builtin_amdgcn_global_load_lds((gas_ptr)(bSrc[1]+kb_), (las_ptr)(&LdsB[(buf)*4096 + (1*256 + w*64)*8]), 16, 0, 0); \
  } while (0)

  STAGEP(0, 0);
  STAGEP(1, 1);
  int cur = 0;
  for (int t = 0; t < nt; ++t) {
    // stage t complete; stage t+1 (if any) stays in flight (counted wait, never a full drain mid-loop)
    if (t + 1 < nt) {
      asm volatile("s_waitcnt vmcnt(4)" ::: "memory");
    } else {
      asm volatile("s_waitcnt vmcnt(0)" ::: "memory");
    }
    __builtin_amdgcn_s_barrier();
    const char* bufA = (const char*)(LdsA + cur*4096);
    const char* bufB = (const char*)(LdsB + cur*4096);
    bf16x8 afrag[4], bfrag[4];
    #pragma unroll
    for (int n = 0; n < 4; ++n)
      bfrag[n] = *(const bf16x8*)(bufB + (wc*64 + n*16 + fr)*64 + ((fq*16) ^ lswz));
    #pragma unroll
    for (int m = 0; m < 4; ++m)
      afrag[m] = *(const bf16x8*)(bufA + (wr*64 + m*16 + fr)*64 + ((fq*16) ^ lswz));
    #pragma unroll
    for (int m = 0; m < 4; ++m)
      #pragma unroll
      for (int n = 0; n < 4; ++n)
        acc[m][n] = __builtin_amdgcn_mfma_f32_16x16x32_bf16(afrag[m], bfrag[n], acc[m][n], 0, 0, 0);
    // all waves' reads of buf[cur] are lgkm-consumed by the MFMAs above; after this barrier
    // it is safe to overwrite buf[cur] with tile t+2
    __builtin_amdgcn_s_barrier();
    if (t + 2 < nt) {
      STAGEP(cur, t + 2);
    }
    cur ^= 1;
  }
#undef STAGEP

  // ---- coalesced epilogue: two 64-row halves staged through LDS (32 KB, exact fit) ----
  float* eps = (float*)LdsRaw;
  #pragma unroll
  for (int h = 0; h < 2; ++h) {
    __syncthreads();
    if (wr == h) {
      #pragma unroll
      for (int n = 0; n < 4; ++n)
        #pragma unroll
        for (int i = 0; i < 4; ++i)
          #pragma unroll
          for (int r = 0; r < 4; ++r) {
            int lrow = i*16 + fq*4 + r;
            int col  = wc*64 + n*16 + fr;
            eps[lrow*128 + (col ^ (((lrow >> 2) & 7) << 2))] = acc[i][n][r];
          }
    }
    __syncthreads();
    #pragma unroll
    for (int p = 0; p < 8; ++p) {
      int idx = p*256 + tid;
      int lrow = idx >> 5, cg = idx & 31;
      int col0 = cg * 4;
      int grow = m0 + h*64 + lrow;
      if (grow < M) {
        f32x4 v = *(const f32x4*)&eps[lrow*128 + (col0 ^ (((lrow >> 2) & 7) << 2))];
        int gcol = n0 + col0;
        if (EPI == 1 || EPI == 2) {
          float4 bv = *(const float4*)&bias[gcol];
          v[0] += bv.x; v[1] += bv.y; v[2] += bv.z; v[3] += bv.w;
        }
        if (EPI == 1) {
          float4 rv = *(const float4*)&Res[(size_t)grow * NN + gcol];
          v[0] += rv.x; v[1] += rv.y; v[2] += rv.z; v[3] += rv.w;
          *(float4*)&((float*)Cout)[(size_t)grow * NN + gcol] = make_float4(v[0], v[1], v[2], v[3]);
        } else if (EPI == 0) {
          *(float4*)&((float*)Cout)[(size_t)grow * NN + gcol] = make_float4(v[0], v[1], v[2], v[3]);
        } else {
          if (EPI == 2) {
            v[0] = gelu_exact(v[0]); v[1] = gelu_exact(v[1]);
            v[2] = gelu_exact(v[2]); v[3] = gelu_exact(v[3]);
          }
          unsigned long long ov = (unsigned long long)pk2(v[0], v[1])
                                | ((unsigned long long)pk2(v[2], v[3]) << 32);
          *(unsigned long long*)&((unsigned short*)Cout)[(size_t)grow * NN + gcol] = ov;
        }
      }
    }
  }
}

// ---------------------------------------------------------------- cls attention (split-K)
#define CLS_CH 7
#define CLS_CHSZ 256
__global__ __launch_bounds__(256) void cls_attn_part(const unsigned short* __restrict__ qkv,
                                                     float* __restrict__ part) {
  int blk = blockIdx.x;
  int c = blk % CLS_CH, bh = blk / CLS_CH;
  int b = bh / H_, h = bh % H_;
  const unsigned short* base = qkv + (size_t)b * N_ * QKVC_ + h * HD_;
  __shared__ float q[HD_];
  __shared__ float s[CLS_CHSZ];
  __shared__ float redm[4], redd[4];
  __shared__ float pvs[4][HD_];
  int tid = threadIdx.x;
  if (tid < HD_) q[tid] = bf2f(base[tid]) * SCALE_;
  __syncthreads();
  int j = c * CLS_CHSZ + tid;
  float sc = -1e30f;
  if (j < N_) {
    const unsigned short* kp = base + (size_t)j * QKVC_ + D_;
    float acc = 0.f;
    #pragma unroll
    for (int cc = 0; cc < 8; ++cc) {
      uint4 kv = *(const uint4*)(kp + cc*8);
      const unsigned short* e = (const unsigned short*)&kv;
      #pragma unroll
      for (int t = 0; t < 8; ++t) acc = fmaf(q[cc*8+t], bf2f(e[t]), acc);
    }
    sc = acc;
  }
  float m = sc;
  #pragma unroll
  for (int o = 32; o > 0; o >>= 1) m = fmaxf(m, __shfl_xor(m, o));
  if ((tid & 63) == 0) redm[tid >> 6] = m;
  __syncthreads();
  m = fmaxf(fmaxf(redm[0], redm[1]), fmaxf(redm[2], redm[3]));
  float p = (j < N_) ? __expf(sc - m) : 0.f;
  s[tid] = p;
  float den = p;
  #pragma unroll
  for (int o = 32; o > 0; o >>= 1) den += __shfl_xor(den, o);
  if ((tid & 63) == 0) redd[tid >> 6] = den;
  __syncthreads();
  float dtot = redd[0] + redd[1] + redd[2] + redd[3];
  int lane = tid & 63, g = tid >> 6;
  float acc = 0.f;
  #pragma unroll 8
  for (int i = 0; i < CLS_CHSZ/4; ++i) {
    int jl = g + 4*i;
    int jj = c * CLS_CHSZ + jl;
    if (jj < N_) acc = fmaf(s[jl], bf2f(base[(size_t)jj * QKVC_ + 2*D_ + lane]), acc);
  }
  pvs[g][lane] = acc;
  __syncthreads();
  if (g == 0) {
    float pv = pvs[0][lane] + pvs[1][lane] + pvs[2][lane] + pvs[3][lane];
    float* pp = part + ((size_t)bh * CLS_CH + c) * 66;
    if (lane == 0) { pp[0] = m; pp[1] = dtot; }
    pp[2 + lane] = pv;
  }
}

__global__ __launch_bounds__(64) void cls_attn_reduce(const float* __restrict__ part,
                                                      unsigned short* __restrict__ att) {
  int bh = blockIdx.x;
  int b = bh / H_, h = bh % H_;
  int lane = threadIdx.x;
  const float* pp = part + (size_t)bh * CLS_CH * 66;
  float m = -1e30f;
  #pragma unroll
  for (int c = 0; c < CLS_CH; ++c) m = fmaxf(m, pp[c*66]);
  float den = 0.f, acc = 0.f;
  #pragma unroll
  for (int c = 0; c < CLS_CH; ++c) {
    float wfac = __expf(pp[c*66] - m);
    den += pp[c*66 + 1] * wfac;
    acc += pp[c*66 + 2 + lane] * wfac;
  }
  att[(size_t)(b * N_) * D_ + h * HD_ + lane] = f2bf(acc / den);
}

// ---------------------------------------------------------------- space attention (MFMA)
__global__ __launch_bounds__(256) void space_attn_mfma(const unsigned short* __restrict__ qkv,
                                                       unsigned short* __restrict__ att) {
  int blk = blockIdx.x;
  int f = blk % F_; int bh = blk / F_;
  int b = bh / H_, h = bh % H_;
  const unsigned short* qbase = qkv + (size_t)b * N_ * QKVC_ + h * HD_;
  __shared__ __align__(16) unsigned short Ksm[208*64];
  __shared__ __align__(16) unsigned short Vtm[64*256];
  __shared__ __align__(16) unsigned short Pm[4*16*256];
  int tid = threadIdx.x;

  for (int c = tid; c < 208*8; c += 256) {
    int j = c >> 3, cb = (c & 7) * 16;
    uint4 val = make_uint4(0,0,0,0);
    if (j < 197) {
      int n = (j == 0) ? 0 : (1 + f*P_ + j - 1);
      val = *(const uint4*)(qbase + (size_t)n*QKVC_ + D_ + cb/2);
    }
    *(uint4*)((char*)Ksm + j*128 + (cb ^ ((j&7)<<4))) = val;
  }
  for (int c = tid; c < 112*8; c += 256) {
    int jj = c % 112, dc = c / 112;
    int j0 = jj * 2;
    uint4 r0 = make_uint4(0,0,0,0), r1 = make_uint4(0,0,0,0);
    if (j0 < 197) {
      int n = (j0 == 0) ? 0 : (1 + f*P_ + j0 - 1);
      r0 = *(const uint4*)(qbase + (size_t)n*QKVC_ + 2*D_ + dc*8);
    }
    if (j0 + 1 < 197) {
      int n = 1 + f*P_ + j0;
      r1 = *(const uint4*)(qbase + (size_t)n*QKVC_ + 2*D_ + dc*8);
    }
    const unsigned short* e0 = (const unsigned short*)&r0;
    const unsigned short* e1 = (const unsigned short*)&r1;
    #pragma unroll
    for (int e = 0; e < 8; ++e) {
      int d = dc*8 + e;
      unsigned int pk = (unsigned int)e0[e] | ((unsigned int)e1[e] << 16);
      *(unsigned int*)((char*)Vtm + d*512 + ((2*j0) ^ ((d&7)<<4))) = pk;
    }
  }
  int w = tid >> 6, l = tid & 63;
  int fr = l & 15, fq = l >> 4;
  char* Pw = (char*)Pm + w * 8192;
  {
    int q = l >> 2, cb = 416 + (l & 3) * 8;
    *(unsigned long long*)(Pw + q*512 + (cb ^ ((q&7)<<4))) = 0ull;
  }
  __syncthreads();

  int swz = (fr & 7) << 4;
  for (int qt = w; qt <= 12; qt += 4) {
    int qrow = qt*16 + fr; if (qrow > 195) qrow = 195;
    int n_q = 1 + f*P_ + qrow;
    bf16x8 qf0 = *(const bf16x8*)(qbase + (size_t)n_q*QKVC_ + fq*8);
    bf16x8 qf1 = *(const bf16x8*)(qbase + (size_t)n_q*QKVC_ + 32 + fq*8);
    f32x4 s[13];
    #pragma unroll
    for (int jt = 0; jt < 13; ++jt) s[jt] = (f32x4){0.f,0.f,0.f,0.f};
    #pragma unroll
    for (int jt = 0; jt < 13; ++jt) {
      bf16x8 a0 = *(const bf16x8*)((char*)Ksm + (jt*16+fr)*128 + ((fq*16) ^ swz));
      s[jt] = __builtin_amdgcn_mfma_f32_16x16x32_bf16(a0, qf0, s[jt], 0, 0, 0);
      bf16x8 a1 = *(const bf16x8*)((char*)Ksm + (jt*16+fr)*128 + ((64 + fq*16) ^ swz));
      s[jt] = __builtin_amdgcn_mfma_f32_16x16x32_bf16(a1, qf1, s[jt], 0, 0, 0);
    }
    float m = -1e30f;
    #pragma unroll
    for (int jt = 0; jt < 13; ++jt) {
      #pragma unroll
      for (int r = 0; r < 4; ++r) {
        if (jt*16 + fq*4 + r < 197) m = fmaxf(m, s[jt][r]);
      }
    }
    m = fmaxf(m, __shfl_xor(m, 16));
    m = fmaxf(m, __shfl_xor(m, 32));
    float den = 0.f;
    #pragma unroll
    for (int jt = 0; jt < 13; ++jt) {
      #pragma unroll
      for (int r = 0; r < 4; ++r) {
        float p = (jt*16 + fq*4 + r < 197) ? __expf((s[jt][r] - m) * SCALE_) : 0.f;
        s[jt][r] = p;
        den += p;
      }
    }
    den += __shfl_xor(den, 16);
    den += __shfl_xor(den, 32);
    #pragma unroll
    for (int jt = 0; jt < 13; ++jt) {
      unsigned long long pv = (unsigned long long)pk2(s[jt][0], s[jt][1])
                            | ((unsigned long long)pk2(s[jt][2], s[jt][3]) << 32);
      *(unsigned long long*)(Pw + fr*512 + ((jt*32 + fq*8) ^ swz)) = pv;
    }
    float rden = 1.0f / den;
    bool wr_ok = (qt*16 + fr) < 196;
    int n_out = 1 + f*P_ + qt*16 + fr;
    #pragma unroll
    for (int dt = 0; dt < 4; ++dt) {
      f32x4 o = (f32x4){0.f,0.f,0.f,0.f};
      #pragma unroll
      for (int ks = 0; ks < 7; ++ks) {
        bf16x8 av = *(const bf16x8*)((char*)Vtm + (dt*16+fr)*512 + ((ks*64 + fq*16) ^ swz));
        bf16x8 bp = *(const bf16x8*)(Pw + fr*512 + ((ks*64 + fq*16) ^ swz));
        o = __builtin_amdgcn_mfma_f32_16x16x32_bf16(av, bp, o, 0, 0, 0);
      }
      if (wr_ok) {
        unsigned long long ov = (unsigned long long)pk2(o[0]*rden, o[1]*rden)
                              | ((unsigned long long)pk2(o[2]*rden, o[3]*rden) << 32);
        *(unsigned long long*)(att + (size_t)(b*N_ + n_out)*D_ + h*HD_ + dt*16 + fq*4) = ov;
      }
    }
  }
}

// ---------------------------------------------------------------- time attention (bf16 qkv)
__global__ __launch_bounds__(256) void time_attn_kernel(const unsigned short* __restrict__ qkv,
                                                        unsigned short* __restrict__ att) {
  int idx = blockIdx.x * 4 + (threadIdx.x >> 6);
  int bh = idx / P_, p = idx % P_;
  int b = bh / H_, h = bh % H_;
  int lane = threadIdx.x & 63;
  const unsigned short* base = qkv + (size_t)b * N_ * QKVC_ + h * HD_ + lane;
  float k[9], v[9];
  k[0] = bf2f(base[D_]);
  v[0] = bf2f(base[2*D_]);
  #pragma unroll
  for (int j = 0; j < 8; ++j) {
    size_t r = (size_t)(1 + j * P_ + p) * QKVC_;
    k[j+1] = bf2f(base[r + D_]);
    v[j+1] = bf2f(base[r + 2*D_]);
  }
  #pragma unroll 1
  for (int f = 0; f < F_; ++f) {
    size_t qr = (size_t)(1 + f * P_ + p) * QKVC_;
    float qd = bf2f(base[qr]) * SCALE_;
    float s[9];
    #pragma unroll
    for (int j = 0; j < 9; ++j) {
      float prod = qd * k[j];
      #pragma unroll
      for (int o = 32; o > 0; o >>= 1) prod += __shfl_xor(prod, o);
      s[j] = prod;
    }
    float m = s[0];
    #pragma unroll
    for (int j = 1; j < 9; ++j) m = fmaxf(m, s[j]);
    float den = 0.f, o_ = 0.f;
    #pragma unroll
    for (int j = 0; j < 9; ++j) {
      float pj = __expf(s[j] - m);
      den += pj;
      o_ = fmaf(pj, v[j], o_);
    }
    att[(size_t)(b * N_ + 1 + f * P_ + p) * D_ + h * HD_ + lane] = f2bf(o_ / den);
  }
}

// ---------------------------------------------------------------- launcher
extern "C" void kernel_launch(void* const* d_in, const int* in_sizes, int n_in,
                              void* d_out, int out_size, void* d_ws, size_t ws_size,
                              hipStream_t stream) {
  const float* x_in     = (const float*)d_in[0];
  const float* qkv_w_t  = (const float*)d_in[1];
  const float* proj_w_t = (const float*)d_in[2];
  const float* proj_b_t = (const float*)d_in[3];
  const float* qkv_w_s  = (const float*)d_in[4];
  const float* proj_w_s = (const float*)d_in[5];
  const float* proj_b_s = (const float*)d_in[6];
  const float* fc1_w    = (const float*)d_in[7];
  const float* fc1_b    = (const float*)d_in[8];
  const float* fc2_w    = (const float*)d_in[9];
  const float* fc2_b    = (const float*)d_in[10];
  const float* ln1_g    = (const float*)d_in[11];
  const float* ln1_b    = (const float*)d_in[12];
  const float* ln2_g    = (const float*)d_in[13];
  const float* ln2_b    = (const float*)d_in[14];
  const float* ln3_g    = (const float*)d_in[15];
  const float* ln3_b    = (const float*)d_in[16];

  float* X_out = (float*)d_out;
  char* ws = (char*)d_ws;
  unsigned short* Wbf = (unsigned short*)ws;
  const size_t WOFF = 18874368;
  unsigned short* QKVbf = (unsigned short*)(ws + WOFF);
  unsigned short* Hbf   = (unsigned short*)(ws + WOFF);
  float*          TR    = (float*)(ws + WOFF + 57839616);
  unsigned short* Abf   = (unsigned short*)(ws + WOFF + 57839616 + 19279872);
  float*          CLSP  = (float*)(ws + WOFF + 57839616 + 19279872 + 9639936);

  unsigned short* wqkv_t = Wbf + 0;
  unsigned short* wproj_t= Wbf + 1769472;
  unsigned short* wqkv_s = Wbf + 2359296;
  unsigned short* wproj_s= Wbf + 4128768;
  unsigned short* wfc1   = Wbf + 4718592;
  unsigned short* wfc2   = Wbf + 7077888;

  dim3 blk(256);
  // 128x128 tile grids (flattened 1-D): gx = ceil(6276/128) = 50
  dim3 g_qkv(50 * 18), g_proj(50 * 6), g_fc1(50 * 24), g_fc2(50 * 6);

  for (int l = 0; l < L_; ++l) {
    const float* X = (l == 0) ? x_in : (const float*)X_out;
    cvt_layer_kernel<<<2048, blk, 0, stream>>>(
        qkv_w_t + (size_t)l*SQKV, proj_w_t + (size_t)l*SPROJ,
        qkv_w_s + (size_t)l*SQKV, proj_w_s + (size_t)l*SPROJ,
        fc1_w + (size_t)l*SFC, fc2_w + (size_t)l*SFC, Wbf);
    // 1. a = LN3(x)
    ln_kernel<<<BN_, blk, 0, stream>>>(X, ln3_g + l*D_, ln3_b + l*D_, Abf);
    // 2. qkv_t (bf16 out)
    mfma_gemmP<3><<<g_qkv, blk, 0, stream>>>(Abf, wqkv_t, nullptr, nullptr, QKVbf, BN_, QKVC_, D_);
    // 3/4. time attention (+ cls)
    cls_attn_part<<<B_*H_*CLS_CH, blk, 0, stream>>>(QKVbf, CLSP);
    cls_attn_reduce<<<B_*H_, dim3(64), 0, stream>>>(CLSP, Abf);
    time_attn_kernel<<<(B_*H_*P_)/4, blk, 0, stream>>>(QKVbf, Abf);
    // 5. time_residual = x + att @ proj_w_t^T + b
    mfma_gemmP<1><<<g_proj, blk, 0, stream>>>(Abf, wproj_t, proj_b_t + l*D_, X, TR, BN_, D_, D_);
    // 6. a = LN1(time_residual)
    ln_kernel<<<BN_, blk, 0, stream>>>(TR, ln1_g + l*D_, ln1_b + l*D_, Abf);
    // 7. qkv_s (bf16 out)
    mfma_gemmP<3><<<g_qkv, blk, 0, stream>>>(Abf, wqkv_s, nullptr, nullptr, QKVbf, BN_, QKVC_, D_);
    // 8/9. space attention (+ cls)
    cls_attn_part<<<B_*H_*CLS_CH, blk, 0, stream>>>(QKVbf, CLSP);
    cls_attn_reduce<<<B_*H_, dim3(64), 0, stream>>>(CLSP, Abf);
    space_attn_mfma<<<B_*H_*F_, blk, 0, stream>>>(QKVbf, Abf);
    // 10. space_residual = x + att @ proj_w_s^T + b
    mfma_gemmP<1><<<g_proj, blk, 0, stream>>>(Abf, wproj_s, proj_b_s + l*D_, X, TR, BN_, D_, D_);
    // 11. a = LN2(space_residual)
    ln_kernel<<<BN_, blk, 0, stream>>>(TR, ln2_g + l*D_, ln2_b + l*D_, Abf);
    // 12. h = gelu(a @ fc1^T + b)  (bf16 out)
    mfma_gemmP<2><<<g_fc1, blk, 0, stream>>>(Abf, wfc1, fc1_b + l*MLP_, nullptr, Hbf, BN_, MLP_, D_);
    // 13. out = space_residual + h @ fc2^T + b
    mfma_gemmP<1><<<g_fc2, blk, 0, stream>>>(Hbf, wfc2, fc2_b + l*D_, TR, X_out, BN_, D_, MLP_);
  }
}